// Round 4
// baseline (1314.701 us; speedup 1.0000x reference)
//
#include <hip/hip_runtime.h>

typedef __attribute__((ext_vector_type(8))) short short8;
typedef __attribute__((ext_vector_type(4))) float f32x4;

// ---- workspace layout (uint16 element offsets from ws base) ----
// LSTM weights stored as hi-plane then lo-plane (hi+lo bf16 ~= fp32),
// PRE-SCALED by -log2e (i,f,o) / -2log2e (g) so the cell update uses raw
// exp2. B-frag tile order: nt = GATE TYPE, wave = unit block of 16.
#define OFF_BXO   64                        // obs Wih B-frags hi[8192]+lo[8192]
#define OFF_BHO   (OFF_BXO + 16384)         // obs Whh B-frags hi[16384]+lo[16384]
#define OFF_BXW   (OFF_BHO + 32768)         // wrf Wih B-frags hi[16384]+lo[16384]
#define OFF_BHW   (OFF_BXW + 32768)         // wrf Whh B-frags hi[16384]+lo[16384]
#define OFF_HW    (OFF_BHW + 32768)         // head weights bf16 (single)
#define OFF_BIASL (OFF_HW + 43008)          // fp32: lstm bias (bih+bhh), scaled
#define OFF_BIASH (OFF_BIASL + 1024)        // fp32: head biases [2][208]
#define OFF_FEAT  (OFF_BIASH + 832)         // feat hi [8192][128] + lo plane

#define SC_IFO  -1.4426950408889634f        // -log2(e)
#define SC_G    -2.8853900817779268f        // -2*log2(e)

__device__ __forceinline__ float b2f(unsigned short u) {
    return __uint_as_float(((unsigned)u) << 16);
}
__device__ __forceinline__ unsigned short f2b(float f) {
    unsigned u = __float_as_uint(f);
    u += 0x7FFFu + ((u >> 16) & 1u);   // RNE
    return (unsigned short)(u >> 16);
}
__device__ __forceinline__ float ldin(const void* p, int idx, int isf) {
    return isf ? ((const float*)p)[idx] : b2f(((const unsigned short*)p)[idx]);
}
__device__ __forceinline__ float exp2_(float x) {
#if __has_builtin(__builtin_amdgcn_exp2f)
    return __builtin_amdgcn_exp2f(x);
#else
    return exp2f(x);
#endif
}
__device__ __forceinline__ f32x4 MFMA(short8 a, short8 b, f32x4 c) {
    return __builtin_amdgcn_mfma_f32_16x16x32_bf16(a, b, c, 0, 0, 0);
}

// ---------------------------------------------------------------------------
// Kernel 0: dtype detector (unchanged).
// ---------------------------------------------------------------------------
__global__ __launch_bounds__(256) void detect_kernel(
    const unsigned short* __restrict__ X, int* __restrict__ flag)
{
    __shared__ int cnt[256];
    int c = 0;
    for (int i = threadIdx.x; i < 2048; i += 256) {
        unsigned short u = X[2 * i];   // EVEN half-word
        c += (((u >> 7) & 0xFF) >= 192);
    }
    cnt[threadIdx.x] = c;
    __syncthreads();
    if (threadIdx.x == 0) {
        int s = 0;
        for (int i = 0; i < 256; ++i) s += cnt[i];
        *flag = (s > 64) ? 1 : 0;
    }
}

// ---------------------------------------------------------------------------
// Kernel 1: weight prep. LSTM weights/biases pre-scaled by the exp2 factors
// (exact transformation: sigmoid(x)=rcp(1+2^(-x*log2e)), tanh via 2^(-2x*log2e)).
// ---------------------------------------------------------------------------
__global__ __launch_bounds__(256) void prep_kernel(
    const void* oWih, const void* oWhh, const void* obih, const void* obhh,
    const void* wWih, const void* wWhh, const void* wbih, const void* wbhh,
    const void* fW1, const void* fb1, const void* fW2, const void* fb2,
    const void* fW3, const void* fb3,
    const void* oW1, const void* ob1, const void* oW2, const void* ob2,
    const void* oW3, const void* ob3,
    unsigned short* __restrict__ ws)
{
    const int isf = ((const int*)ws)[0];
    const int gid = blockIdx.x * 256 + threadIdx.x;
    const int gsz = gridDim.x * 256;

    unsigned short* BXO = ws + OFF_BXO;
    unsigned short* BHO = ws + OFF_BHO;
    unsigned short* BXW = ws + OFF_BXW;
    unsigned short* BHW = ws + OFF_BHW;
    unsigned short* HW  = ws + OFF_HW;

    // obs Wih: i = wave*2048 + nt*512 + lane*8 + j ; g = nt*64 + wave*16 + col
    for (int i = gid; i < 8192; i += gsz) {
        int j = i & 7, lane = (i >> 3) & 63, nt = (i >> 9) & 3, wave = i >> 11;
        int g = nt * 64 + wave * 16 + (lane & 15);
        int k = ((lane >> 4) << 3) + j;
        float s = ((g >> 6) == 2) ? SC_G : SC_IFO;
        float w = ldin(oWih, g * 32 + k, isf) * s;
        unsigned short hi = f2b(w);
        BXO[i] = hi; BXO[8192 + i] = f2b(w - b2f(hi));
    }
    // obs Whh
    for (int i = gid; i < 16384; i += gsz) {
        int j = i & 7, lane = (i >> 3) & 63, nt = (i >> 9) & 3;
        int kt = (i >> 11) & 1, wave = i >> 12;
        int g = nt * 64 + wave * 16 + (lane & 15);
        int k = kt * 32 + ((lane >> 4) << 3) + j;
        float s = ((g >> 6) == 2) ? SC_G : SC_IFO;
        float w = ldin(oWhh, g * 64 + k, isf) * s;
        unsigned short hi = f2b(w);
        BHO[i] = hi; BHO[16384 + i] = f2b(w - b2f(hi));
    }
    // wrf Wih (zero-pad k>=56)
    for (int i = gid; i < 16384; i += gsz) {
        int j = i & 7, lane = (i >> 3) & 63, nt = (i >> 9) & 3;
        int wave = (i >> 11) & 3, kt2 = i >> 13;
        int g = nt * 64 + wave * 16 + (lane & 15);
        int k = kt2 * 32 + ((lane >> 4) << 3) + j;
        float s = ((g >> 6) == 2) ? SC_G : SC_IFO;
        float w = (k < 56) ? ldin(wWih, g * 56 + k, isf) * s : 0.f;
        unsigned short hi = f2b(w);
        BXW[i] = hi; BXW[16384 + i] = f2b(w - b2f(hi));
    }
    // wrf Whh
    for (int i = gid; i < 16384; i += gsz) {
        int j = i & 7, lane = (i >> 3) & 63, nt = (i >> 9) & 3;
        int kt = (i >> 11) & 1, wave = i >> 12;
        int g = nt * 64 + wave * 16 + (lane & 15);
        int k = kt * 32 + ((lane >> 4) << 3) + j;
        float s = ((g >> 6) == 2) ? SC_G : SC_IFO;
        float w = ldin(wWhh, g * 64 + k, isf) * s;
        unsigned short hi = f2b(w);
        BHW[i] = hi; BHW[16384 + i] = f2b(w - b2f(hi));
    }
    // head weights, plain row-major bf16
    for (int i = gid; i < 12288; i += gsz) HW[i]         = f2b(ldin(fW1, i, isf));
    for (int i = gid; i < 6144;  i += gsz) HW[12288 + i] = f2b(ldin(fW2, i, isf));
    for (int i = gid; i < 3072;  i += gsz) HW[18432 + i] = f2b(ldin(fW3, i, isf));
    for (int i = gid; i < 12288; i += gsz) HW[21504 + i] = f2b(ldin(oW1, i, isf));
    for (int i = gid; i < 6144;  i += gsz) HW[33792 + i] = f2b(ldin(oW2, i, isf));
    for (int i = gid; i < 3072;  i += gsz) HW[39936 + i] = f2b(ldin(oW3, i, isf));
    // lstm biases (bih+bhh), fp32, pre-scaled
    float* BL = (float*)(ws + OFF_BIASL);
    for (int i = gid; i < 256; i += gsz) {
        float s = ((i >> 6) == 2) ? SC_G : SC_IFO;
        BL[i] = (ldin(obih, i, isf) + ldin(obhh, i, isf)) * s;
    }
    for (int i = gid; i < 256; i += gsz) {
        float s = ((i >> 6) == 2) ? SC_G : SC_IFO;
        BL[256 + i] = (ldin(wbih, i, isf) + ldin(wbhh, i, isf)) * s;
    }
    // head biases, fp32
    float* BB = (float*)(ws + OFF_BIASH);
    for (int i = gid; i < 96; i += gsz) BB[i]       = ldin(fb1, i, isf);
    for (int i = gid; i < 64; i += gsz) BB[96 + i]  = ldin(fb2, i, isf);
    for (int i = gid; i < 48; i += gsz) BB[160 + i] = ldin(fb3, i, isf);
    for (int i = gid; i < 96; i += gsz) BB[208 + i] = ldin(ob1, i, isf);
    for (int i = gid; i < 64; i += gsz) BB[304 + i] = ldin(ob2, i, isf);
    for (int i = gid; i < 48; i += gsz) BB[368 + i] = ldin(ob3, i, isf);
}

// ---------------------------------------------------------------------------
// Kernel 2: persistent-per-block LSTM. acc init = bias (no adds); exp2-based
// gates (weights pre-scaled); x prefetched to registers one chunk ahead
// (global-load latency hidden under the 4 compute steps); per-step barrier is
// lgkmcnt-only so prefetch loads stay in flight. LDS 32 KB.
// ---------------------------------------------------------------------------
#define TCH 4
__global__ __launch_bounds__(256, 4) void lstm_kernel(
    const void* __restrict__ Xo, const void* __restrict__ Xw,
    unsigned short* __restrict__ ws)
{
    __shared__ unsigned short xbuf[2][TCH][8][16][8];   // [hi/lo][t][ktile][physrow][j]
    __shared__ unsigned short hfrag[2][2][2][4][16][8]; // [par][hi/lo][kt][quadA][physrow][j]

    const int tid  = threadIdx.x;
    const int wave = tid >> 6, lane = tid & 63;
    const int quad = lane >> 4, m16 = lane & 15;
    const bool isw = blockIdx.x >= 512;
    const int blk  = isw ? (int)blockIdx.x - 512 : (int)blockIdx.x;
    const int n0   = blk * 16;
    const int isf  = ((const int*)ws)[0];

    const void* x = isw ? Xw : Xo;
    const unsigned short* BX = ws + (isw ? OFF_BXW : OFF_BXO);
    const unsigned short* BH = ws + (isw ? OFF_BHW : OFF_BHO);
    const float* BL = (const float*)(ws + OFF_BIASL) + (isw ? 256 : 0);
    unsigned short* featH = ws + OFF_FEAT;
    unsigned short* featL = featH + 8192 * 128;
    const int C       = isw ? 56 : 32;
    const int Cpad    = isw ? 64 : 32;
    const int cshift  = isw ? 6 : 5;
    const int niter   = isw ? 4 : 2;          // staging iterations (256 thr)
    const int xloOff  = isw ? 16384 : 8192;   // lo-plane offset within BX
    const int featOff = isw ? 64 : 0;

    // --- B fragments (constant over all 72 steps) ---
    short8 BhH[2][4], BhL[2][4];
#pragma unroll
    for (int kt = 0; kt < 2; ++kt)
#pragma unroll
        for (int nt = 0; nt < 4; ++nt) {
            int idx = ((wave * 2 + kt) * 4 + nt) * 512 + lane * 8;
            BhH[kt][nt] = *(const short8*)&BH[idx];
            BhL[kt][nt] = *(const short8*)&BH[16384 + idx];
        }
    short8 BxH0[4], BxL0[4], BxH1[4], BxL1[4];
#pragma unroll
    for (int nt = 0; nt < 4; ++nt) {
        int idx = (wave * 4 + nt) * 512 + lane * 8;
        BxH0[nt] = *(const short8*)&BX[idx];
        BxL0[nt] = *(const short8*)&BX[xloOff + idx];
    }
    if (isw) {
#pragma unroll
        for (int nt = 0; nt < 4; ++nt) {
            int idx = (wave * 4 + nt) * 512 + lane * 8;
            BxH1[nt] = *(const short8*)&BX[8192 + idx];
            BxL1[nt] = *(const short8*)&BX[xloOff + 8192 + idx];
        }
    }

    // this lane owns unit u for 4 batch rows (quad*4 + r)
    const int u = wave * 16 + m16;
    const float bias_i = BL[u];
    const float bias_f = BL[u + 64];
    const float bias_g = BL[u + 128];
    const float bias_o = BL[u + 192];
    float c4[4] = {0.f, 0.f, 0.f, 0.f};

    // hfrag write coords for unit u
    const int ktw = wave >> 1;
    const int qaw = ((wave & 1) << 1) | (m16 >> 3);
    const int jw  = m16 & 7;
    const int chunkbit = (m16 >> 3) << 2;   // (qaw&1)<<2
    // hfrag read physical row for this lane (row = m16, k-quad = quad)
    const int prr = ((((m16 & 3) << 2) | (m16 >> 2)) ^ ((quad & 1) << 2));

    for (int i = tid; i < 2 * 2 * 2 * 4 * 16 * 8; i += 256)
        ((unsigned short*)hfrag)[i] = 0;
    // (first chunk's staging barrier also covers hfrag zero-init)

    // x prefetch registers (one chunk ahead)
    float pv[4][TCH];
    auto LOADX = [&](int ch) {
        const int t0x = ch * TCH;
#pragma unroll
        for (int it = 0; it < 4; ++it) {
            if (it < niter) {
                int i = tid + it * 256;
                int n = i >> cshift, c = i & (Cpad - 1);
                if (c < C) {
                    size_t off = ((size_t)(n0 + n) * C + c) * 72 + t0x;
                    if (isf) {
                        f32x4 u0 = *(const f32x4*)((const float*)x + off); // 16B-aligned
                        pv[it][0] = u0[0]; pv[it][1] = u0[1];
                        pv[it][2] = u0[2]; pv[it][3] = u0[3];
                    } else {
                        const unsigned short* p = (const unsigned short*)x + off;
#pragma unroll
                        for (int j = 0; j < TCH; ++j) pv[it][j] = b2f(p[j]);
                    }
                } else {
#pragma unroll
                    for (int j = 0; j < TCH; ++j) pv[it][j] = 0.f;
                }
            }
        }
    };

    LOADX(0);
    int par = 0;
    for (int chunk = 0; chunk < 18; ++chunk) {
        // ---- stage prefetched x -> xbuf hi+lo (truncation split) ----
#pragma unroll
        for (int it = 0; it < 4; ++it) {
            if (it < niter) {
                int i = tid + it * 256;
                int n = i >> cshift, c = i & (Cpad - 1);
                int kt = c >> 3, pr = n ^ kt;
#pragma unroll
                for (int tt = 0; tt < TCH; ++tt) {
                    float v = pv[it][tt];
                    unsigned hu = __float_as_uint(v);
                    unsigned short hi = (unsigned short)(hu >> 16);
                    float hiv = __uint_as_float(hu & 0xFFFF0000u);
                    unsigned short lo = (unsigned short)(__float_as_uint(v - hiv) >> 16);
                    xbuf[0][tt][kt][pr][c & 7] = hi;
                    xbuf[1][tt][kt][pr][c & 7] = lo;
                }
            }
        }
        asm volatile("s_waitcnt lgkmcnt(0)\ns_barrier" ::: "memory");
        if (chunk < 17) LOADX(chunk + 1);   // in flight across the 4 steps

        for (int tt = 0; tt < TCH; ++tt) {
            const int t = chunk * TCH + tt;
            // ---- MFMA: gates = x_t @ Wih^T + h @ Whh^T + bias (C-init) ----
            f32x4 acc[4] = {{bias_i, bias_i, bias_i, bias_i},
                            {bias_f, bias_f, bias_f, bias_f},
                            {bias_g, bias_g, bias_g, bias_g},
                            {bias_o, bias_o, bias_o, bias_o}};
            {
                short8 axh = *(const short8*)&xbuf[0][tt][quad][m16 ^ quad][0];
                short8 axl = *(const short8*)&xbuf[1][tt][quad][m16 ^ quad][0];
#pragma unroll
                for (int nt = 0; nt < 4; ++nt) {
                    acc[nt] = MFMA(axh, BxH0[nt], acc[nt]);
                    acc[nt] = MFMA(axl, BxH0[nt], acc[nt]);
                    acc[nt] = MFMA(axh, BxL0[nt], acc[nt]);
                }
            }
            if (isw) {
                short8 axh = *(const short8*)&xbuf[0][tt][4 + quad][m16 ^ (4 + quad)][0];
                short8 axl = *(const short8*)&xbuf[1][tt][4 + quad][m16 ^ (4 + quad)][0];
#pragma unroll
                for (int nt = 0; nt < 4; ++nt) {
                    acc[nt] = MFMA(axh, BxH1[nt], acc[nt]);
                    acc[nt] = MFMA(axl, BxH1[nt], acc[nt]);
                    acc[nt] = MFMA(axh, BxL1[nt], acc[nt]);
                }
            }
#pragma unroll
            for (int kt = 0; kt < 2; ++kt) {
                short8 ahi = *(const short8*)&hfrag[par][0][kt][quad][prr][0];
                short8 alo = *(const short8*)&hfrag[par][1][kt][quad][prr][0];
#pragma unroll
                for (int nt = 0; nt < 4; ++nt) {
                    acc[nt] = MFMA(ahi, BhH[kt][nt], acc[nt]);
                    acc[nt] = MFMA(alo, BhH[kt][nt], acc[nt]);
                    acc[nt] = MFMA(ahi, BhL[kt][nt], acc[nt]);
                }
            }

            // ---- cell update, in-register; pre-activations are exp2-scaled
            // (sigmoid(x) = rcp(1+2^y), tanh(x) = 2*rcp(1+2^y)-1) ----
#pragma unroll
            for (int r = 0; r < 4; ++r) {
                float iv = __builtin_amdgcn_rcpf(1.0f + exp2_(acc[0][r]));
                float fv = __builtin_amdgcn_rcpf(1.0f + exp2_(acc[1][r]));
                float gv = 2.0f * __builtin_amdgcn_rcpf(1.0f + exp2_(acc[2][r])) - 1.0f;
                float ov = __builtin_amdgcn_rcpf(1.0f + exp2_(acc[3][r]));
                float c  = fv * c4[r] + iv * gv;
                c4[r]    = c;
                float tc = 2.0f * __builtin_amdgcn_rcpf(1.0f + exp2_(c * SC_G)) - 1.0f;
                float h  = ov * tc;
                // truncated hi/lo split (pair-exact to ~2^-17; lo absorbs it)
                unsigned hu = __float_as_uint(h);
                unsigned short hi = (unsigned short)(hu >> 16);
                float hiv = __uint_as_float(hu & 0xFFFF0000u);
                unsigned short lo = (unsigned short)(__float_as_uint(h - hiv) >> 16);
                int pr = ((r << 2) | quad) ^ chunkbit;
                hfrag[par ^ 1][0][ktw][qaw][pr][jw] = hi;
                hfrag[par ^ 1][1][ktw][qaw][pr][jw] = lo;
                if (t == 71) {
                    int m = quad * 4 + r;
                    featH[(size_t)(n0 + m) * 128 + featOff + u] = hi;
                    featL[(size_t)(n0 + m) * 128 + featOff + u] = lo;
                }
            }
            asm volatile("s_waitcnt lgkmcnt(0)\ns_barrier" ::: "memory");
            par ^= 1;
        }
    }
}

// ---------------------------------------------------------------------------
// Kernel 3: MLP heads, ONE WAVE per block (16 rows) -> 512 independent blocks,
// no inter-wave barriers (wave-local lgkmcnt ordering only).
// Output dtype follows input dtype: fp32 if isf else bf16. [N][2][48].
// ---------------------------------------------------------------------------
__global__ __launch_bounds__(64) void heads_kernel(
    const unsigned short* __restrict__ ws, void* __restrict__ out)
{
    __shared__ unsigned short afrag[4][4][16][8];  // [ktile][quad][m][j]
    const int lane = threadIdx.x;
    const int quad = lane >> 4, m16 = lane & 15;
    const int r0   = blockIdx.x * 16;
    const int isf  = ((const int*)ws)[0];

    const unsigned short* HW    = ws + OFF_HW;
    const float*          BB    = (const float*)(ws + OFF_BIASH);
    const unsigned short* featH = ws + OFF_FEAT;
    const unsigned short* featL = featH + 8192 * 128;

    short8 fh[4], fl[4];
#pragma unroll
    for (int kt = 0; kt < 4; ++kt) {
        size_t o = (size_t)(r0 + m16) * 128 + kt * 32 + quad * 8;
        fh[kt] = *(const short8*)&featH[o];
        fl[kt] = *(const short8*)&featL[o];
    }

    for (int head = 0; head < 2; ++head) {
        const unsigned short* W1 = HW + (head ? 21504 : 0);
        const unsigned short* W2 = W1 + 12288;
        const unsigned short* W3 = W2 + 6144;
        const float* b1 = BB + head * 208;
        const float* b2 = b1 + 96;
        const float* b3 = b2 + 64;

        // L1: K=128, O=96, relu
        f32x4 a1[6] = {{0,0,0,0},{0,0,0,0},{0,0,0,0},{0,0,0,0},{0,0,0,0},{0,0,0,0}};
#pragma unroll
        for (int kt = 0; kt < 4; ++kt)
#pragma unroll
            for (int nt = 0; nt < 6; ++nt) {
                short8 bw = *(const short8*)
                    &W1[(nt * 16 + m16) * 128 + kt * 32 + quad * 8];
                a1[nt] = MFMA(fh[kt], bw, a1[nt]);
                a1[nt] = MFMA(fl[kt], bw, a1[nt]);
            }
#pragma unroll
        for (int nt = 0; nt < 6; ++nt) {
            int u = nt * 16 + m16;
            float bv = b1[u];
#pragma unroll
            for (int r = 0; r < 4; ++r) {
                float v = a1[nt][r] + bv;
                v = v > 0.f ? v : 0.f;
                afrag[u >> 5][(u >> 3) & 3][quad * 4 + r][u & 7] = f2b(v);
            }
        }
        asm volatile("s_waitcnt lgkmcnt(0)" ::: "memory");

        // L2: K=96, O=64, relu
        f32x4 a2[4] = {{0,0,0,0},{0,0,0,0},{0,0,0,0},{0,0,0,0}};
#pragma unroll
        for (int kt = 0; kt < 3; ++kt) {
            short8 a = *(const short8*)&afrag[kt][quad][m16][0];
#pragma unroll
            for (int nt = 0; nt < 4; ++nt) {
                short8 bw = *(const short8*)
                    &W2[(nt * 16 + m16) * 96 + kt * 32 + quad * 8];
                a2[nt] = MFMA(a, bw, a2[nt]);
            }
        }
        asm volatile("s_waitcnt lgkmcnt(0)" ::: "memory");
#pragma unroll
        for (int nt = 0; nt < 4; ++nt) {
            int u = nt * 16 + m16;
            float bv = b2[u];
#pragma unroll
            for (int r = 0; r < 4; ++r) {
                float v = a2[nt][r] + bv;
                v = v > 0.f ? v : 0.f;
                afrag[u >> 5][(u >> 3) & 3][quad * 4 + r][u & 7] = f2b(v);
            }
        }
        asm volatile("s_waitcnt lgkmcnt(0)" ::: "memory");

        // L3: K=64, O=48, no relu -> out[n][head][u], dtype per isf
        f32x4 a3[3] = {{0,0,0,0},{0,0,0,0},{0,0,0,0}};
#pragma unroll
        for (int kt = 0; kt < 2; ++kt) {
            short8 a = *(const short8*)&afrag[kt][quad][m16][0];
#pragma unroll
            for (int nt = 0; nt < 3; ++nt) {
                short8 bw = *(const short8*)
                    &W3[(nt * 16 + m16) * 64 + kt * 32 + quad * 8];
                a3[nt] = MFMA(a, bw, a3[nt]);
            }
        }
#pragma unroll
        for (int nt = 0; nt < 3; ++nt) {
            int u = nt * 16 + m16;
            float bv = b3[u];
#pragma unroll
            for (int r = 0; r < 4; ++r) {
                int row = quad * 4 + r;
                size_t idx = (size_t)(r0 + row) * 96 + head * 48 + u;
                float v = a3[nt][r] + bv;
                if (isf) ((float*)out)[idx] = v;
                else     ((unsigned short*)out)[idx] = f2b(v);
            }
        }
        asm volatile("s_waitcnt lgkmcnt(0)" ::: "memory");
    }
}

// ---------------------------------------------------------------------------
extern "C" void kernel_launch(void* const* d_in, const int* in_sizes, int n_in,
                              void* d_out, int out_size, void* d_ws, size_t ws_size,
                              hipStream_t stream)
{
    unsigned short* ws = (unsigned short*)d_ws;

    detect_kernel<<<1, 256, 0, stream>>>((const unsigned short*)d_in[0], (int*)d_ws);
    prep_kernel<<<64, 256, 0, stream>>>(
        d_in[2], d_in[3], d_in[4], d_in[5],
        d_in[6], d_in[7], d_in[8], d_in[9],
        d_in[10], d_in[11], d_in[12], d_in[13], d_in[14], d_in[15],
        d_in[16], d_in[17], d_in[18], d_in[19], d_in[20], d_in[21],
        ws);
    lstm_kernel<<<1024, 256, 0, stream>>>(d_in[0], d_in[1], ws);
    heads_kernel<<<512, 64, 0, stream>>>(ws, d_out);
}

// Round 5
// 463.564 us; speedup vs baseline: 2.8361x; 2.8361x over previous
//
#include <hip/hip_runtime.h>

typedef __attribute__((ext_vector_type(8))) short short8;
typedef __attribute__((ext_vector_type(4))) float f32x4;

// ---- workspace layout (uint16 element offsets from ws base) ----
// LSTM weights stored as hi-plane then lo-plane (hi+lo bf16 ~= fp32),
// PRE-SCALED by -log2e (i,f,o) / -2log2e (g) so the cell update uses raw
// exp2. B-frag tile order: nt = GATE TYPE, wave = unit block of 16.
#define OFF_BXO   64                        // obs Wih B-frags hi[8192]+lo[8192]
#define OFF_BHO   (OFF_BXO + 16384)         // obs Whh B-frags hi[16384]+lo[16384]
#define OFF_BXW   (OFF_BHO + 32768)         // wrf Wih B-frags hi[16384]+lo[16384]
#define OFF_BHW   (OFF_BXW + 32768)         // wrf Whh B-frags hi[16384]+lo[16384]
#define OFF_HW    (OFF_BHW + 32768)         // head weights bf16 (single)
#define OFF_BIASL (OFF_HW + 43008)          // fp32: lstm bias (bih+bhh), scaled
#define OFF_BIASH (OFF_BIASL + 1024)        // fp32: head biases [2][208]
#define OFF_FEAT  (OFF_BIASH + 832)         // feat hi [8192][128] + lo plane

#define SC_IFO  -1.4426950408889634f        // -log2(e)
#define SC_G    -2.8853900817779268f        // -2*log2(e)

__device__ __forceinline__ float b2f(unsigned short u) {
    return __uint_as_float(((unsigned)u) << 16);
}
__device__ __forceinline__ unsigned short f2b(float f) {
    unsigned u = __float_as_uint(f);
    u += 0x7FFFu + ((u >> 16) & 1u);   // RNE
    return (unsigned short)(u >> 16);
}
__device__ __forceinline__ float ldin(const void* p, int idx, int isf) {
    return isf ? ((const float*)p)[idx] : b2f(((const unsigned short*)p)[idx]);
}
__device__ __forceinline__ float exp2_(float x) {
#if __has_builtin(__builtin_amdgcn_exp2f)
    return __builtin_amdgcn_exp2f(x);
#else
    return exp2f(x);
#endif
}
__device__ __forceinline__ f32x4 MFMA(short8 a, short8 b, f32x4 c) {
    return __builtin_amdgcn_mfma_f32_16x16x32_bf16(a, b, c, 0, 0, 0);
}

// ---------------------------------------------------------------------------
// Kernel 0: dtype detector (unchanged).
// ---------------------------------------------------------------------------
__global__ __launch_bounds__(256) void detect_kernel(
    const unsigned short* __restrict__ X, int* __restrict__ flag)
{
    __shared__ int cnt[256];
    int c = 0;
    for (int i = threadIdx.x; i < 2048; i += 256) {
        unsigned short u = X[2 * i];   // EVEN half-word
        c += (((u >> 7) & 0xFF) >= 192);
    }
    cnt[threadIdx.x] = c;
    __syncthreads();
    if (threadIdx.x == 0) {
        int s = 0;
        for (int i = 0; i < 256; ++i) s += cnt[i];
        *flag = (s > 64) ? 1 : 0;
    }
}

// ---------------------------------------------------------------------------
// Kernel 1: weight prep. LSTM weights/biases pre-scaled by the exp2 factors
// (exact transformation: sigmoid(x)=rcp(1+2^(-x*log2e)), tanh via 2^(-2x*log2e)).
// ---------------------------------------------------------------------------
__global__ __launch_bounds__(256) void prep_kernel(
    const void* oWih, const void* oWhh, const void* obih, const void* obhh,
    const void* wWih, const void* wWhh, const void* wbih, const void* wbhh,
    const void* fW1, const void* fb1, const void* fW2, const void* fb2,
    const void* fW3, const void* fb3,
    const void* oW1, const void* ob1, const void* oW2, const void* ob2,
    const void* oW3, const void* ob3,
    unsigned short* __restrict__ ws)
{
    const int isf = ((const int*)ws)[0];
    const int gid = blockIdx.x * 256 + threadIdx.x;
    const int gsz = gridDim.x * 256;

    unsigned short* BXO = ws + OFF_BXO;
    unsigned short* BHO = ws + OFF_BHO;
    unsigned short* BXW = ws + OFF_BXW;
    unsigned short* BHW = ws + OFF_BHW;
    unsigned short* HW  = ws + OFF_HW;

    // obs Wih: i = wave*2048 + nt*512 + lane*8 + j ; g = nt*64 + wave*16 + col
    for (int i = gid; i < 8192; i += gsz) {
        int j = i & 7, lane = (i >> 3) & 63, nt = (i >> 9) & 3, wave = i >> 11;
        int g = nt * 64 + wave * 16 + (lane & 15);
        int k = ((lane >> 4) << 3) + j;
        float s = ((g >> 6) == 2) ? SC_G : SC_IFO;
        float w = ldin(oWih, g * 32 + k, isf) * s;
        unsigned short hi = f2b(w);
        BXO[i] = hi; BXO[8192 + i] = f2b(w - b2f(hi));
    }
    // obs Whh
    for (int i = gid; i < 16384; i += gsz) {
        int j = i & 7, lane = (i >> 3) & 63, nt = (i >> 9) & 3;
        int kt = (i >> 11) & 1, wave = i >> 12;
        int g = nt * 64 + wave * 16 + (lane & 15);
        int k = kt * 32 + ((lane >> 4) << 3) + j;
        float s = ((g >> 6) == 2) ? SC_G : SC_IFO;
        float w = ldin(oWhh, g * 64 + k, isf) * s;
        unsigned short hi = f2b(w);
        BHO[i] = hi; BHO[16384 + i] = f2b(w - b2f(hi));
    }
    // wrf Wih (zero-pad k>=56)
    for (int i = gid; i < 16384; i += gsz) {
        int j = i & 7, lane = (i >> 3) & 63, nt = (i >> 9) & 3;
        int wave = (i >> 11) & 3, kt2 = i >> 13;
        int g = nt * 64 + wave * 16 + (lane & 15);
        int k = kt2 * 32 + ((lane >> 4) << 3) + j;
        float s = ((g >> 6) == 2) ? SC_G : SC_IFO;
        float w = (k < 56) ? ldin(wWih, g * 56 + k, isf) * s : 0.f;
        unsigned short hi = f2b(w);
        BXW[i] = hi; BXW[16384 + i] = f2b(w - b2f(hi));
    }
    // wrf Whh
    for (int i = gid; i < 16384; i += gsz) {
        int j = i & 7, lane = (i >> 3) & 63, nt = (i >> 9) & 3;
        int kt = (i >> 11) & 1, wave = i >> 12;
        int g = nt * 64 + wave * 16 + (lane & 15);
        int k = kt * 32 + ((lane >> 4) << 3) + j;
        float s = ((g >> 6) == 2) ? SC_G : SC_IFO;
        float w = ldin(wWhh, g * 64 + k, isf) * s;
        unsigned short hi = f2b(w);
        BHW[i] = hi; BHW[16384 + i] = f2b(w - b2f(hi));
    }
    // head weights, plain row-major bf16
    for (int i = gid; i < 12288; i += gsz) HW[i]         = f2b(ldin(fW1, i, isf));
    for (int i = gid; i < 6144;  i += gsz) HW[12288 + i] = f2b(ldin(fW2, i, isf));
    for (int i = gid; i < 3072;  i += gsz) HW[18432 + i] = f2b(ldin(fW3, i, isf));
    for (int i = gid; i < 12288; i += gsz) HW[21504 + i] = f2b(ldin(oW1, i, isf));
    for (int i = gid; i < 6144;  i += gsz) HW[33792 + i] = f2b(ldin(oW2, i, isf));
    for (int i = gid; i < 3072;  i += gsz) HW[39936 + i] = f2b(ldin(oW3, i, isf));
    // lstm biases (bih+bhh), fp32, pre-scaled
    float* BL = (float*)(ws + OFF_BIASL);
    for (int i = gid; i < 256; i += gsz) {
        float s = ((i >> 6) == 2) ? SC_G : SC_IFO;
        BL[i] = (ldin(obih, i, isf) + ldin(obhh, i, isf)) * s;
    }
    for (int i = gid; i < 256; i += gsz) {
        float s = ((i >> 6) == 2) ? SC_G : SC_IFO;
        BL[256 + i] = (ldin(wbih, i, isf) + ldin(wbhh, i, isf)) * s;
    }
    // head biases, fp32
    float* BB = (float*)(ws + OFF_BIASH);
    for (int i = gid; i < 96; i += gsz) BB[i]       = ldin(fb1, i, isf);
    for (int i = gid; i < 64; i += gsz) BB[96 + i]  = ldin(fb2, i, isf);
    for (int i = gid; i < 48; i += gsz) BB[160 + i] = ldin(fb3, i, isf);
    for (int i = gid; i < 96; i += gsz) BB[208 + i] = ldin(ob1, i, isf);
    for (int i = gid; i < 64; i += gsz) BB[304 + i] = ldin(ob2, i, isf);
    for (int i = gid; i < 48; i += gsz) BB[368 + i] = ldin(ob3, i, isf);
}

// ---------------------------------------------------------------------------
// Kernel 2: persistent-per-block LSTM. acc init = bias; exp2-based gates;
// x prefetched to registers one chunk ahead; per-step barrier is lgkm-only.
// NOTE: plain __launch_bounds__(256) — forcing min-waves=4 caps VGPR at 64
// and spills ~40 regs to scratch (R4: 3.8 GB scratch traffic, 3.5x slower).
// ---------------------------------------------------------------------------
#define TCH 4
__global__ __launch_bounds__(256) void lstm_kernel(
    const void* __restrict__ Xo, const void* __restrict__ Xw,
    unsigned short* __restrict__ ws)
{
    __shared__ unsigned short xbuf[2][TCH][8][16][8];   // [hi/lo][t][ktile][physrow][j]
    __shared__ unsigned short hfrag[2][2][2][4][16][8]; // [par][hi/lo][kt][quadA][physrow][j]

    const int tid  = threadIdx.x;
    const int wave = tid >> 6, lane = tid & 63;
    const int quad = lane >> 4, m16 = lane & 15;
    const bool isw = blockIdx.x >= 512;
    const int blk  = isw ? (int)blockIdx.x - 512 : (int)blockIdx.x;
    const int n0   = blk * 16;
    const int isf  = ((const int*)ws)[0];

    const void* x = isw ? Xw : Xo;
    const unsigned short* BX = ws + (isw ? OFF_BXW : OFF_BXO);
    const unsigned short* BH = ws + (isw ? OFF_BHW : OFF_BHO);
    const float* BL = (const float*)(ws + OFF_BIASL) + (isw ? 256 : 0);
    unsigned short* featH = ws + OFF_FEAT;
    unsigned short* featL = featH + 8192 * 128;
    const int C       = isw ? 56 : 32;
    const int Cpad    = isw ? 64 : 32;
    const int cshift  = isw ? 6 : 5;
    const int niter   = isw ? 4 : 2;          // staging iterations (256 thr)
    const int xloOff  = isw ? 16384 : 8192;   // lo-plane offset within BX
    const int featOff = isw ? 64 : 0;

    // --- B fragments (constant over all 72 steps) ---
    short8 BhH[2][4], BhL[2][4];
#pragma unroll
    for (int kt = 0; kt < 2; ++kt)
#pragma unroll
        for (int nt = 0; nt < 4; ++nt) {
            int idx = ((wave * 2 + kt) * 4 + nt) * 512 + lane * 8;
            BhH[kt][nt] = *(const short8*)&BH[idx];
            BhL[kt][nt] = *(const short8*)&BH[16384 + idx];
        }
    short8 BxH0[4], BxL0[4], BxH1[4], BxL1[4];
#pragma unroll
    for (int nt = 0; nt < 4; ++nt) {
        int idx = (wave * 4 + nt) * 512 + lane * 8;
        BxH0[nt] = *(const short8*)&BX[idx];
        BxL0[nt] = *(const short8*)&BX[xloOff + idx];
    }
    if (isw) {
#pragma unroll
        for (int nt = 0; nt < 4; ++nt) {
            int idx = (wave * 4 + nt) * 512 + lane * 8;
            BxH1[nt] = *(const short8*)&BX[8192 + idx];
            BxL1[nt] = *(const short8*)&BX[xloOff + 8192 + idx];
        }
    }

    // this lane owns unit u for 4 batch rows (quad*4 + r)
    const int u = wave * 16 + m16;
    const float bias_i = BL[u];
    const float bias_f = BL[u + 64];
    const float bias_g = BL[u + 128];
    const float bias_o = BL[u + 192];
    float c4[4] = {0.f, 0.f, 0.f, 0.f};

    // hfrag write coords for unit u
    const int ktw = wave >> 1;
    const int qaw = ((wave & 1) << 1) | (m16 >> 3);
    const int jw  = m16 & 7;
    const int chunkbit = (m16 >> 3) << 2;   // (qaw&1)<<2
    // hfrag read physical row for this lane (row = m16, k-quad = quad)
    const int prr = ((((m16 & 3) << 2) | (m16 >> 2)) ^ ((quad & 1) << 2));

    for (int i = tid; i < 2 * 2 * 2 * 4 * 16 * 8; i += 256)
        ((unsigned short*)hfrag)[i] = 0;
    // (first chunk's staging barrier also covers hfrag zero-init)

    // x prefetch registers (one chunk ahead)
    float pv[4][TCH];
    auto LOADX = [&](int ch) {
        const int t0x = ch * TCH;
#pragma unroll
        for (int it = 0; it < 4; ++it) {
            if (it < niter) {
                int i = tid + it * 256;
                int n = i >> cshift, c = i & (Cpad - 1);
                if (c < C) {
                    size_t off = ((size_t)(n0 + n) * C + c) * 72 + t0x;
                    if (isf) {
                        f32x4 u0 = *(const f32x4*)((const float*)x + off); // 16B-aligned
                        pv[it][0] = u0[0]; pv[it][1] = u0[1];
                        pv[it][2] = u0[2]; pv[it][3] = u0[3];
                    } else {
                        const unsigned short* p = (const unsigned short*)x + off;
#pragma unroll
                        for (int j = 0; j < TCH; ++j) pv[it][j] = b2f(p[j]);
                    }
                } else {
#pragma unroll
                    for (int j = 0; j < TCH; ++j) pv[it][j] = 0.f;
                }
            }
        }
    };

    LOADX(0);
    int par = 0;
    for (int chunk = 0; chunk < 18; ++chunk) {
        // ---- stage prefetched x -> xbuf hi+lo (truncation split) ----
#pragma unroll
        for (int it = 0; it < 4; ++it) {
            if (it < niter) {
                int i = tid + it * 256;
                int n = i >> cshift, c = i & (Cpad - 1);
                int kt = c >> 3, pr = n ^ kt;
#pragma unroll
                for (int tt = 0; tt < TCH; ++tt) {
                    float v = pv[it][tt];
                    unsigned hu = __float_as_uint(v);
                    unsigned short hi = (unsigned short)(hu >> 16);
                    float hiv = __uint_as_float(hu & 0xFFFF0000u);
                    unsigned short lo = (unsigned short)(__float_as_uint(v - hiv) >> 16);
                    xbuf[0][tt][kt][pr][c & 7] = hi;
                    xbuf[1][tt][kt][pr][c & 7] = lo;
                }
            }
        }
        asm volatile("s_waitcnt lgkmcnt(0)\ns_barrier" ::: "memory");
        if (chunk < 17) LOADX(chunk + 1);   // in flight across the 4 steps

        for (int tt = 0; tt < TCH; ++tt) {
            const int t = chunk * TCH + tt;
            // ---- MFMA: gates = x_t @ Wih^T + h @ Whh^T + bias (C-init) ----
            f32x4 acc[4] = {{bias_i, bias_i, bias_i, bias_i},
                            {bias_f, bias_f, bias_f, bias_f},
                            {bias_g, bias_g, bias_g, bias_g},
                            {bias_o, bias_o, bias_o, bias_o}};
            {
                short8 axh = *(const short8*)&xbuf[0][tt][quad][m16 ^ quad][0];
                short8 axl = *(const short8*)&xbuf[1][tt][quad][m16 ^ quad][0];
#pragma unroll
                for (int nt = 0; nt < 4; ++nt) {
                    acc[nt] = MFMA(axh, BxH0[nt], acc[nt]);
                    acc[nt] = MFMA(axl, BxH0[nt], acc[nt]);
                    acc[nt] = MFMA(axh, BxL0[nt], acc[nt]);
                }
            }
            if (isw) {
                short8 axh = *(const short8*)&xbuf[0][tt][4 + quad][m16 ^ (4 + quad)][0];
                short8 axl = *(const short8*)&xbuf[1][tt][4 + quad][m16 ^ (4 + quad)][0];
#pragma unroll
                for (int nt = 0; nt < 4; ++nt) {
                    acc[nt] = MFMA(axh, BxH1[nt], acc[nt]);
                    acc[nt] = MFMA(axl, BxH1[nt], acc[nt]);
                    acc[nt] = MFMA(axh, BxL1[nt], acc[nt]);
                }
            }
#pragma unroll
            for (int kt = 0; kt < 2; ++kt) {
                short8 ahi = *(const short8*)&hfrag[par][0][kt][quad][prr][0];
                short8 alo = *(const short8*)&hfrag[par][1][kt][quad][prr][0];
#pragma unroll
                for (int nt = 0; nt < 4; ++nt) {
                    acc[nt] = MFMA(ahi, BhH[kt][nt], acc[nt]);
                    acc[nt] = MFMA(alo, BhH[kt][nt], acc[nt]);
                    acc[nt] = MFMA(ahi, BhL[kt][nt], acc[nt]);
                }
            }

            // ---- cell update, in-register; pre-activations are exp2-scaled
            // (sigmoid(x) = rcp(1+2^y), tanh(x) = 2*rcp(1+2^y)-1) ----
#pragma unroll
            for (int r = 0; r < 4; ++r) {
                float iv = __builtin_amdgcn_rcpf(1.0f + exp2_(acc[0][r]));
                float fv = __builtin_amdgcn_rcpf(1.0f + exp2_(acc[1][r]));
                float gv = 2.0f * __builtin_amdgcn_rcpf(1.0f + exp2_(acc[2][r])) - 1.0f;
                float ov = __builtin_amdgcn_rcpf(1.0f + exp2_(acc[3][r]));
                float c  = fv * c4[r] + iv * gv;
                c4[r]    = c;
                float tc = 2.0f * __builtin_amdgcn_rcpf(1.0f + exp2_(c * SC_G)) - 1.0f;
                float h  = ov * tc;
                // truncated hi/lo split (pair-exact to ~2^-17; lo absorbs it)
                unsigned hu = __float_as_uint(h);
                unsigned short hi = (unsigned short)(hu >> 16);
                float hiv = __uint_as_float(hu & 0xFFFF0000u);
                unsigned short lo = (unsigned short)(__float_as_uint(h - hiv) >> 16);
                int pr = ((r << 2) | quad) ^ chunkbit;
                hfrag[par ^ 1][0][ktw][qaw][pr][jw] = hi;
                hfrag[par ^ 1][1][ktw][qaw][pr][jw] = lo;
                if (t == 71) {
                    int m = quad * 4 + r;
                    featH[(size_t)(n0 + m) * 128 + featOff + u] = hi;
                    featL[(size_t)(n0 + m) * 128 + featOff + u] = lo;
                }
            }
            asm volatile("s_waitcnt lgkmcnt(0)\ns_barrier" ::: "memory");
            par ^= 1;
        }
    }
}

// ---------------------------------------------------------------------------
// Kernel 3: MLP heads, ONE WAVE per block (16 rows) -> 512 independent blocks,
// no inter-wave barriers (wave-local lgkmcnt ordering only).
// Output dtype follows input dtype: fp32 if isf else bf16. [N][2][48].
// ---------------------------------------------------------------------------
__global__ __launch_bounds__(64) void heads_kernel(
    const unsigned short* __restrict__ ws, void* __restrict__ out)
{
    __shared__ unsigned short afrag[4][4][16][8];  // [ktile][quad][m][j]
    const int lane = threadIdx.x;
    const int quad = lane >> 4, m16 = lane & 15;
    const int r0   = blockIdx.x * 16;
    const int isf  = ((const int*)ws)[0];

    const unsigned short* HW    = ws + OFF_HW;
    const float*          BB    = (const float*)(ws + OFF_BIASH);
    const unsigned short* featH = ws + OFF_FEAT;
    const unsigned short* featL = featH + 8192 * 128;

    short8 fh[4], fl[4];
#pragma unroll
    for (int kt = 0; kt < 4; ++kt) {
        size_t o = (size_t)(r0 + m16) * 128 + kt * 32 + quad * 8;
        fh[kt] = *(const short8*)&featH[o];
        fl[kt] = *(const short8*)&featL[o];
    }

    for (int head = 0; head < 2; ++head) {
        const unsigned short* W1 = HW + (head ? 21504 : 0);
        const unsigned short* W2 = W1 + 12288;
        const unsigned short* W3 = W2 + 6144;
        const float* b1 = BB + head * 208;
        const float* b2 = b1 + 96;
        const float* b3 = b2 + 64;

        // L1: K=128, O=96, relu
        f32x4 a1[6] = {{0,0,0,0},{0,0,0,0},{0,0,0,0},{0,0,0,0},{0,0,0,0},{0,0,0,0}};
#pragma unroll
        for (int kt = 0; kt < 4; ++kt)
#pragma unroll
            for (int nt = 0; nt < 6; ++nt) {
                short8 bw = *(const short8*)
                    &W1[(nt * 16 + m16) * 128 + kt * 32 + quad * 8];
                a1[nt] = MFMA(fh[kt], bw, a1[nt]);
                a1[nt] = MFMA(fl[kt], bw, a1[nt]);
            }
#pragma unroll
        for (int nt = 0; nt < 6; ++nt) {
            int u = nt * 16 + m16;
            float bv = b1[u];
#pragma unroll
            for (int r = 0; r < 4; ++r) {
                float v = a1[nt][r] + bv;
                v = v > 0.f ? v : 0.f;
                afrag[u >> 5][(u >> 3) & 3][quad * 4 + r][u & 7] = f2b(v);
            }
        }
        asm volatile("s_waitcnt lgkmcnt(0)" ::: "memory");

        // L2: K=96, O=64, relu
        f32x4 a2[4] = {{0,0,0,0},{0,0,0,0},{0,0,0,0},{0,0,0,0}};
#pragma unroll
        for (int kt = 0; kt < 3; ++kt) {
            short8 a = *(const short8*)&afrag[kt][quad][m16][0];
#pragma unroll
            for (int nt = 0; nt < 4; ++nt) {
                short8 bw = *(const short8*)
                    &W2[(nt * 16 + m16) * 96 + kt * 32 + quad * 8];
                a2[nt] = MFMA(a, bw, a2[nt]);
            }
        }
        asm volatile("s_waitcnt lgkmcnt(0)" ::: "memory");
#pragma unroll
        for (int nt = 0; nt < 4; ++nt) {
            int u = nt * 16 + m16;
            float bv = b2[u];
#pragma unroll
            for (int r = 0; r < 4; ++r) {
                float v = a2[nt][r] + bv;
                v = v > 0.f ? v : 0.f;
                afrag[u >> 5][(u >> 3) & 3][quad * 4 + r][u & 7] = f2b(v);
            }
        }
        asm volatile("s_waitcnt lgkmcnt(0)" ::: "memory");

        // L3: K=64, O=48, no relu -> out[n][head][u], dtype per isf
        f32x4 a3[3] = {{0,0,0,0},{0,0,0,0},{0,0,0,0}};
#pragma unroll
        for (int kt = 0; kt < 2; ++kt) {
            short8 a = *(const short8*)&afrag[kt][quad][m16][0];
#pragma unroll
            for (int nt = 0; nt < 3; ++nt) {
                short8 bw = *(const short8*)
                    &W3[(nt * 16 + m16) * 64 + kt * 32 + quad * 8];
                a3[nt] = MFMA(a, bw, a3[nt]);
            }
        }
#pragma unroll
        for (int nt = 0; nt < 3; ++nt) {
            int u = nt * 16 + m16;
            float bv = b3[u];
#pragma unroll
            for (int r = 0; r < 4; ++r) {
                int row = quad * 4 + r;
                size_t idx = (size_t)(r0 + row) * 96 + head * 48 + u;
                float v = a3[nt][r] + bv;
                if (isf) ((float*)out)[idx] = v;
                else     ((unsigned short*)out)[idx] = f2b(v);
            }
        }
        asm volatile("s_waitcnt lgkmcnt(0)" ::: "memory");
    }
}

// ---------------------------------------------------------------------------
extern "C" void kernel_launch(void* const* d_in, const int* in_sizes, int n_in,
                              void* d_out, int out_size, void* d_ws, size_t ws_size,
                              hipStream_t stream)
{
    unsigned short* ws = (unsigned short*)d_ws;

    detect_kernel<<<1, 256, 0, stream>>>((const unsigned short*)d_in[0], (int*)d_ws);
    prep_kernel<<<64, 256, 0, stream>>>(
        d_in[2], d_in[3], d_in[4], d_in[5],
        d_in[6], d_in[7], d_in[8], d_in[9],
        d_in[10], d_in[11], d_in[12], d_in[13], d_in[14], d_in[15],
        d_in[16], d_in[17], d_in[18], d_in[19], d_in[20], d_in[21],
        ws);
    lstm_kernel<<<1024, 256, 0, stream>>>(d_in[0], d_in[1], ws);
    heads_kernel<<<512, 64, 0, stream>>>(ws, d_out);
}